// Round 8
// baseline (152.566 us; speedup 1.0000x reference)
//
#include <hip/hip_runtime.h>
#include <math.h>

#define B_   8
#define CIN  256
#define L_   1024
#define NH_  8
#define DH_  32

typedef __attribute__((ext_vector_type(8))) short short8;
typedef __attribute__((ext_vector_type(4))) short short4v;
typedef __attribute__((ext_vector_type(4))) float f32x4;
typedef __attribute__((ext_vector_type(4))) unsigned int uint4v;
typedef __attribute__((ext_vector_type(2))) unsigned int uint2v;

__device__ inline short f2bf_hu(float f) {       // bf16 half-up, 2 ops
    union { float f; unsigned u; } v; v.f = f;
    return (short)((v.u + 0x8000u) >> 16);
}
// pack bf16(a) | bf16(b)<<16 : 2 adds + 1 v_perm
__device__ inline unsigned pkbf2(float a, float b) {
    union { float f; unsigned u; } x, y; x.f = a; y.f = b;
    return __builtin_amdgcn_perm(y.u + 0x8000u, x.u + 0x8000u, 0x07060302u);
}

// ---------------------------------------------------------------------------
// QKV GEMM with fused transpose+cast of x (round-7 validated core).
// Q,K -> qkT[b][l][512] (o<512); V -> vT[b][h][dv][l] (transposed for attn
// B-frags). Tile 64(l) x 128(o): blockIdx.y 0..3 = Q/K, 4..5 = V.
// ---------------------------------------------------------------------------
__global__ __launch_bounds__(256) void qkv_gemm(
    const float* __restrict__ x, const float* __restrict__ w,
    const float* __restrict__ bias, short* __restrict__ qkT,
    short* __restrict__ vT)
{
    __shared__ short Xs[64][40];
    __shared__ short Wt[128][40];
    const int t = threadIdx.x, lane = t & 63, wv = t >> 6;
    const int n = lane & 15, quad = lane >> 4;
    const int b = blockIdx.z, o0 = blockIdx.y * 128, l0 = blockIdx.x * 64;

    float bias_r[8];
    #pragma unroll
    for (int nf = 0; nf < 8; nf++) bias_r[nf] = bias[o0 + nf * 16 + n];

    f32x4 acc[8];
    #pragma unroll
    for (int nf = 0; nf < 8; nf++) acc[nf] = (f32x4){0.f, 0.f, 0.f, 0.f};

    const int cS = t >> 3, lsS = (t & 7) * 8;       // X stage roles

    for (int c0 = 0; c0 < CIN; c0 += 32) {
        {   // X stage: 32c x 64l fp32, coalesced along l; swizzled transpose
            const float* xp = &x[(((size_t)b * CIN + c0 + cS) << 10) + l0 + lsS];
            const float4 xa = *(const float4*)xp;
            const float4 xb = *(const float4*)(xp + 4);
            const float vals[8] = {xa.x, xa.y, xa.z, xa.w, xb.x, xb.y, xb.z, xb.w};
            #pragma unroll
            for (int k = 0; k < 8; k++) {
                const int l = lsS + k;
                const int col = (((cS >> 3) ^ (l & 3)) << 3) | (cS & 7);
                Xs[l][col] = f2bf_hu(vals[k]);
            }
        }
        {   // W tile: 128x32, fp32 -> bf16 packed, b128 writes
            const int o = t >> 1, cs = (t & 1) * 16;
            const float* wp = &w[(size_t)(o0 + o) * CIN + c0 + cs];
            const float4 w0 = *(const float4*)(wp);
            const float4 w1 = *(const float4*)(wp + 4);
            const float4 w2 = *(const float4*)(wp + 8);
            const float4 w3 = *(const float4*)(wp + 12);
            uint4v pa = { pkbf2(w0.x, w0.y), pkbf2(w0.z, w0.w),
                          pkbf2(w1.x, w1.y), pkbf2(w1.z, w1.w) };
            uint4v pb = { pkbf2(w2.x, w2.y), pkbf2(w2.z, w2.w),
                          pkbf2(w3.x, w3.y), pkbf2(w3.z, w3.w) };
            *(uint4v*)&Wt[o][cs]     = pa;
            *(uint4v*)&Wt[o][cs + 8] = pb;
        }
        __syncthreads();

        const int arow = wv * 16 + n;
        const short8 af = *(const short8*)&Xs[arow][(quad ^ (arow & 3)) * 8];
        #pragma unroll
        for (int nf = 0; nf < 8; nf++) {
            const short8 bf = *(const short8*)&Wt[nf * 16 + n][quad * 8];
            acc[nf] = __builtin_amdgcn_mfma_f32_16x16x32_bf16(af, bf, acc[nf], 0, 0, 0);
        }
        __syncthreads();
    }

    if (o0 < 512) {      // Q,K -> qkT [b][l][512]
        #pragma unroll
        for (int reg = 0; reg < 4; reg++) {
            const size_t l = l0 + wv * 16 + quad * 4 + reg;
            short* row = qkT + ((((size_t)b << 10) + l) << 9) + o0 + n;
            #pragma unroll
            for (int nf = 0; nf < 8; nf++)
                row[nf * 16] = f2bf_hu(acc[nf][reg] + bias_r[nf]);
        }
    } else {             // V -> vT [b][h][dv][l]
        #pragma unroll
        for (int reg = 0; reg < 4; reg++) {
            const size_t l = l0 + wv * 16 + quad * 4 + reg;
            #pragma unroll
            for (int nf = 0; nf < 8; nf++) {
                const int ov = o0 - 512 + nf * 16 + n;   // 0..255
                vT[(((size_t)(b << 3) << 5) + ov << 10) + l] =
                    f2bf_hu(acc[nf][reg] + bias_r[nf]);
            }
        }
    }
}

// ---------------------------------------------------------------------------
// Proj GEMM: out[b][o][l] = w[o][:]·aT[b][l][:] + bias[o] + resid[b][o][l]
// Tile 64(o) x 64(l). Grid 16x4x8 = 512 blocks = 2/CU exact. (round-5)
// ---------------------------------------------------------------------------
__global__ __launch_bounds__(256) void proj_gemm(
    const short* __restrict__ aT, const float* __restrict__ w,
    const float* __restrict__ bias, const float* __restrict__ resid,
    float* __restrict__ out)
{
    __shared__ short Xs[64][40];
    __shared__ short Wt[64][40];
    const int t = threadIdx.x, lane = t & 63, wv = t >> 6;
    const int n = lane & 15, quad = lane >> 4;
    const int b = blockIdx.z, o0 = blockIdx.y * 64, l0 = blockIdx.x * 64;

    float bias_r[4];
    #pragma unroll
    for (int reg = 0; reg < 4; reg++) bias_r[reg] = bias[o0 + wv * 16 + quad * 4 + reg];

    f32x4 acc[4];
    #pragma unroll
    for (int nf = 0; nf < 4; nf++) acc[nf] = (f32x4){0.f, 0.f, 0.f, 0.f};

    for (int c0 = 0; c0 < CIN; c0 += 32) {
        {   // aT tile 64x32 bf16
            const int l = t >> 2, cs = (t & 3) * 8;
            *(uint4v*)&Xs[l][cs] =
                *(const uint4v*)&aT[(((size_t)b << 10) + l0 + l) * CIN + c0 + cs];
        }
        {   // W tile 64x32, 8 floats per thread
            const int o = t >> 2, cs = (t & 3) * 8;
            const float* wp = &w[(size_t)(o0 + o) * CIN + c0 + cs];
            const float4 a4 = *(const float4*)(wp);
            const float4 b4 = *(const float4*)(wp + 4);
            uint4v pw = { pkbf2(a4.x, a4.y), pkbf2(a4.z, a4.w),
                          pkbf2(b4.x, b4.y), pkbf2(b4.z, b4.w) };
            *(uint4v*)&Wt[o][cs] = pw;
        }
        __syncthreads();

        const short8 af = *(const short8*)&Wt[wv * 16 + n][quad * 8];
        #pragma unroll
        for (int nf = 0; nf < 4; nf++) {
            const short8 bf = *(const short8*)&Xs[nf * 16 + n][quad * 8];
            acc[nf] = __builtin_amdgcn_mfma_f32_16x16x32_bf16(af, bf, acc[nf], 0, 0, 0);
        }
        __syncthreads();
    }

    #pragma unroll
    for (int reg = 0; reg < 4; reg++) {
        const int o = o0 + wv * 16 + quad * 4 + reg;
        #pragma unroll
        for (int nf = 0; nf < 4; nf++) {
            const size_t off = (((size_t)b * CIN + o) << 10) + l0 + nf * 16 + n;
            out[off] = acc[nf][reg] + bias_r[reg] + resid[off];
        }
    }
}

// ---------------------------------------------------------------------------
// Flash attention v4: ALL operands direct from global (Q/K from qkT [l][512],
// V from vT [dv][l] transposed). LDS holds only the wave-private P tile ->
// ZERO barriers in the K-loop. Fixed-shift softmax; ones-column denominator
// in registers. Software-pipelined one j-tile ahead.
// ---------------------------------------------------------------------------
__global__ __launch_bounds__(256) void attn_mfma(
    const short* __restrict__ qkT, const short* __restrict__ vT,
    short* __restrict__ attnoT)
{
    __shared__ __align__(16) char umem[64 * 88 * 2];
    short (*Ss)[88] = (short(*)[88])umem;          // [i][j] bf16 P (wave-private rows)
    float (*OtT)[38] = (float(*)[38])umem;         // [i][dv] fp32 epilogue

    const int t = threadIdx.x, lane = t & 63, wv = t >> 6;
    const int n = lane & 15, quad = lane >> 4;
    const int b = blockIdx.z, h = blockIdx.y, i0 = blockIdx.x * 64;

    const short* qbase = qkT + (((size_t)b << 10) << 9) + h * DH_;
    const short* kbase = qbase + 256;
    const short* vtb   = vT + ((size_t)((b << 3) + h) << 15);   // [dv][l], row 1024

    const short8 qa = *(const short8*)&qbase[(size_t)(i0 + wv * 16 + n) << 9 | (quad * 8)];

    short8 vf2;   // ones-column B-frag: B[k][n]=1 iff n==0
    {
        const short one = (n == 0) ? (short)0x3F80 : (short)0;
        #pragma unroll
        for (int u = 0; u < 8; u++) vf2[u] = one;
    }

    f32x4 o_acc[3];
    #pragma unroll
    for (int nf = 0; nf < 3; nf++) o_acc[nf] = (f32x4){0.f, 0.f, 0.f, 0.f};

    const float K1 = 0.25503510f;    // (1/sqrt(32)) * log2(e)
    const float K2 = 11.54156036f;   // 8 * log2(e)

    // ---- prologue: K and V fragments for tile 0 ----
    short8 kf[4], vf[2][2];
    #pragma unroll
    for (int f = 0; f < 4; f++)
        kf[f] = *(const short8*)&kbase[(size_t)(f * 16 + n) << 9 | (quad * 8)];
    #pragma unroll
    for (int kk = 0; kk < 2; kk++)
        #pragma unroll
        for (int nf = 0; nf < 2; nf++)
            vf[kk][nf] = *(const short8*)&vtb[((nf * 16 + n) << 10) + kk * 32 + quad * 8];

    for (int it = 0; it < 16; it++) {
        short8 kf_n[4], vf_n[2][2];
        if (it < 15) {     // prefetch tile it+1
            const int j0n = (it + 1) * 64;
            #pragma unroll
            for (int f = 0; f < 4; f++)
                kf_n[f] = *(const short8*)&kbase[(size_t)(j0n + f * 16 + n) << 9 | (quad * 8)];
            #pragma unroll
            for (int kk = 0; kk < 2; kk++)
                #pragma unroll
                for (int nf = 0; nf < 2; nf++)
                    vf_n[kk][nf] = *(const short8*)&vtb[((nf * 16 + n) << 10) + j0n + kk * 32 + quad * 8];
        }

        // ---- S^T = K Q^T : lane holds S[i=wv*16+n][j=f*16+quad*4+r] ----
        #pragma unroll
        for (int f = 0; f < 4; f++) {
            f32x4 z = {0.f, 0.f, 0.f, 0.f};
            const f32x4 s = __builtin_amdgcn_mfma_f32_16x16x32_bf16(kf[f], qa, z, 0, 0, 0);
            const float p0 = exp2f(fmaf(s[0], K1, -K2));
            const float p1 = exp2f(fmaf(s[1], K1, -K2));
            const float p2 = exp2f(fmaf(s[2], K1, -K2));
            const float p3 = exp2f(fmaf(s[3], K1, -K2));
            uint2v pk = { pkbf2(p0, p1), pkbf2(p2, p3) };
            *(uint2v*)&Ss[wv * 16 + n][f * 16 + quad * 4] = pk;
        }
        // wave-private Ss rows: in-wave DS ordering, no barrier

        // ---- O += P V (vf2 = ones column -> denominator) ----
        #pragma unroll
        for (int kk = 0; kk < 2; kk++) {
            const short8 pf = *(const short8*)&Ss[wv * 16 + n][kk * 32 + quad * 8];
            #pragma unroll
            for (int nf = 0; nf < 2; nf++)
                o_acc[nf] = __builtin_amdgcn_mfma_f32_16x16x32_bf16(pf, vf[kk][nf], o_acc[nf], 0, 0, 0);
            o_acc[2] = __builtin_amdgcn_mfma_f32_16x16x32_bf16(pf, vf2, o_acc[2], 0, 0, 0);
        }

        #pragma unroll
        for (int f = 0; f < 4; f++) kf[f] = kf_n[f];
        #pragma unroll
        for (int kk = 0; kk < 2; kk++)
            #pragma unroll
            for (int nf = 0; nf < 2; nf++) vf[kk][nf] = vf_n[kk][nf];
    }

    __syncthreads();   // all PV reads of Ss done before OtT overwrites umem
    #pragma unroll
    for (int r = 0; r < 4; r++) {
        const float lv  = __shfl(o_acc[2][r], lane & 48, 64);
        const float inv = 1.f / lv;
        const int il = wv * 16 + quad * 4 + r;
        OtT[il][n]      = o_acc[0][r] * inv;
        OtT[il][16 + n] = o_acc[1][r] * inv;
    }
    __syncthreads();
    short* ob = attnoT + (((size_t)b << 10) + i0) * CIN + h * DH_;
    #pragma unroll
    for (int r = 0; r < 2; r++) {
        const int idx = t + r * 256;
        const int l = idx >> 3, cs = (idx & 7) * 4;
        uint2v pv;
        pv.x = pkbf2(OtT[l][cs],     OtT[l][cs + 1]);
        pv.y = pkbf2(OtT[l][cs + 2], OtT[l][cs + 3]);
        *(uint2v*)&ob[(size_t)l * CIN + cs] = pv;
    }
}

// ---------------------------------------------------------------------------
extern "C" void kernel_launch(void* const* d_in, const int* in_sizes, int n_in,
                              void* d_out, int out_size, void* d_ws, size_t ws_size,
                              hipStream_t stream) {
    const float* x      = (const float*)d_in[0];
    const float* w_qkv  = (const float*)d_in[1];
    const float* b_qkv  = (const float*)d_in[2];
    const float* w_proj = (const float*)d_in[3];
    const float* b_proj = (const float*)d_in[4];
    float* out = (float*)d_out;

    short* qkT    = (short*)d_ws;                          // 8 MB  [b][l][512]
    short* vT     = qkT + (size_t)B_ * L_ * 512;           // 4 MB  [b][h][dv][l]
    short* attnoT = vT  + (size_t)B_ * CIN * L_;           // 4 MB  [b][l][256]

    qkv_gemm<<<dim3(16, 6, B_), 256, 0, stream>>>(x, w_qkv, b_qkv, qkT, vT);
    attn_mfma<<<dim3(16, NH_, B_), 256, 0, stream>>>(qkT, vT, attnoT);
    proj_gemm<<<dim3(16, 4, B_), 256, 0, stream>>>(attnoT, w_proj, b_proj, x, out);
}

// Round 9
// 128.615 us; speedup vs baseline: 1.1862x; 1.1862x over previous
//
#include <hip/hip_runtime.h>
#include <math.h>

#define B_   8
#define CIN  256
#define L_   1024
#define NH_  8
#define DH_  32

typedef __attribute__((ext_vector_type(8))) short short8;
typedef __attribute__((ext_vector_type(4))) short short4v;
typedef __attribute__((ext_vector_type(4))) float f32x4;
typedef __attribute__((ext_vector_type(4))) unsigned int uint4v;
typedef __attribute__((ext_vector_type(2))) unsigned int uint2v;

__device__ inline short f2bf_hu(float f) {       // bf16 half-up, 2 ops
    union { float f; unsigned u; } v; v.f = f;
    return (short)((v.u + 0x8000u) >> 16);
}
// pack bf16(a) | bf16(b)<<16 : 2 adds + 1 v_perm
__device__ inline unsigned pkbf2(float a, float b) {
    union { float f; unsigned u; } x, y; x.f = a; y.f = b;
    return __builtin_amdgcn_perm(y.u + 0x8000u, x.u + 0x8000u, 0x07060302u);
}

// ---------------------------------------------------------------------------
// QKV GEMM with fused transpose+cast of x (round-7 validated).
// qkvT[b][l][o] = x[b][:,l]·w_qkv[o][:] + bias[o], bf16, [l][768] layout.
// Tile 64(l) x 128(o), K=32. Grid 16x6x8 = 768 blocks = 3/CU exact.
// ---------------------------------------------------------------------------
__global__ __launch_bounds__(256) void qkv_gemm(
    const float* __restrict__ x, const float* __restrict__ w,
    const float* __restrict__ bias, short* __restrict__ qkvT)
{
    __shared__ short Xs[64][40];
    __shared__ short Wt[128][40];
    const int t = threadIdx.x, lane = t & 63, wv = t >> 6;
    const int n = lane & 15, quad = lane >> 4;
    const int b = blockIdx.z, o0 = blockIdx.y * 128, l0 = blockIdx.x * 64;

    float bias_r[8];
    #pragma unroll
    for (int nf = 0; nf < 8; nf++) bias_r[nf] = bias[o0 + nf * 16 + n];

    f32x4 acc[8];
    #pragma unroll
    for (int nf = 0; nf < 8; nf++) acc[nf] = (f32x4){0.f, 0.f, 0.f, 0.f};

    const int cS = t >> 3, lsS = (t & 7) * 8;       // X stage roles

    for (int c0 = 0; c0 < CIN; c0 += 32) {
        {   // X stage: 32c x 64l fp32, coalesced along l; swizzled transpose
            const float* xp = &x[(((size_t)b * CIN + c0 + cS) << 10) + l0 + lsS];
            const float4 xa = *(const float4*)xp;
            const float4 xb = *(const float4*)(xp + 4);
            const float vals[8] = {xa.x, xa.y, xa.z, xa.w, xb.x, xb.y, xb.z, xb.w};
            #pragma unroll
            for (int k = 0; k < 8; k++) {
                const int l = lsS + k;
                const int col = (((cS >> 3) ^ (l & 3)) << 3) | (cS & 7);
                Xs[l][col] = f2bf_hu(vals[k]);
            }
        }
        {   // W tile: 128x32, fp32 -> bf16 packed, b128 writes
            const int o = t >> 1, cs = (t & 1) * 16;
            const float* wp = &w[(size_t)(o0 + o) * CIN + c0 + cs];
            const float4 w0 = *(const float4*)(wp);
            const float4 w1 = *(const float4*)(wp + 4);
            const float4 w2 = *(const float4*)(wp + 8);
            const float4 w3 = *(const float4*)(wp + 12);
            uint4v pa = { pkbf2(w0.x, w0.y), pkbf2(w0.z, w0.w),
                          pkbf2(w1.x, w1.y), pkbf2(w1.z, w1.w) };
            uint4v pb = { pkbf2(w2.x, w2.y), pkbf2(w2.z, w2.w),
                          pkbf2(w3.x, w3.y), pkbf2(w3.z, w3.w) };
            *(uint4v*)&Wt[o][cs]     = pa;
            *(uint4v*)&Wt[o][cs + 8] = pb;
        }
        __syncthreads();

        const int arow = wv * 16 + n;
        const short8 af = *(const short8*)&Xs[arow][(quad ^ (arow & 3)) * 8];
        #pragma unroll
        for (int nf = 0; nf < 8; nf++) {
            const short8 bf = *(const short8*)&Wt[nf * 16 + n][quad * 8];
            acc[nf] = __builtin_amdgcn_mfma_f32_16x16x32_bf16(af, bf, acc[nf], 0, 0, 0);
        }
        __syncthreads();
    }

    #pragma unroll
    for (int reg = 0; reg < 4; reg++) {
        const size_t l = l0 + wv * 16 + quad * 4 + reg;
        short* row = qkvT + (((size_t)b << 10) + l) * 768 + o0 + n;
        #pragma unroll
        for (int nf = 0; nf < 8; nf++)
            row[nf * 16] = f2bf_hu(acc[nf][reg] + bias_r[nf]);
    }
}

// ---------------------------------------------------------------------------
// Proj GEMM: out[b][o][l] = w[o][:]·aT[b][l][:] + bias[o] + resid[b][o][l]
// Tile 64(o) x 64(l). Grid 16x4x8 = 512 blocks = 2/CU exact. (round-5)
// ---------------------------------------------------------------------------
__global__ __launch_bounds__(256) void proj_gemm(
    const short* __restrict__ aT, const float* __restrict__ w,
    const float* __restrict__ bias, const float* __restrict__ resid,
    float* __restrict__ out)
{
    __shared__ short Xs[64][40];
    __shared__ short Wt[64][40];
    const int t = threadIdx.x, lane = t & 63, wv = t >> 6;
    const int n = lane & 15, quad = lane >> 4;
    const int b = blockIdx.z, o0 = blockIdx.y * 64, l0 = blockIdx.x * 64;

    float bias_r[4];
    #pragma unroll
    for (int reg = 0; reg < 4; reg++) bias_r[reg] = bias[o0 + wv * 16 + quad * 4 + reg];

    f32x4 acc[4];
    #pragma unroll
    for (int nf = 0; nf < 4; nf++) acc[nf] = (f32x4){0.f, 0.f, 0.f, 0.f};

    for (int c0 = 0; c0 < CIN; c0 += 32) {
        {   // aT tile 64x32 bf16
            const int l = t >> 2, cs = (t & 3) * 8;
            *(uint4v*)&Xs[l][cs] =
                *(const uint4v*)&aT[(((size_t)b << 10) + l0 + l) * CIN + c0 + cs];
        }
        {   // W tile 64x32, 8 floats per thread
            const int o = t >> 2, cs = (t & 3) * 8;
            const float* wp = &w[(size_t)(o0 + o) * CIN + c0 + cs];
            const float4 a4 = *(const float4*)(wp);
            const float4 b4 = *(const float4*)(wp + 4);
            uint4v pw = { pkbf2(a4.x, a4.y), pkbf2(a4.z, a4.w),
                          pkbf2(b4.x, b4.y), pkbf2(b4.z, b4.w) };
            *(uint4v*)&Wt[o][cs] = pw;
        }
        __syncthreads();

        const short8 af = *(const short8*)&Wt[wv * 16 + n][quad * 8];
        #pragma unroll
        for (int nf = 0; nf < 4; nf++) {
            const short8 bf = *(const short8*)&Xs[nf * 16 + n][quad * 8];
            acc[nf] = __builtin_amdgcn_mfma_f32_16x16x32_bf16(af, bf, acc[nf], 0, 0, 0);
        }
        __syncthreads();
    }

    #pragma unroll
    for (int reg = 0; reg < 4; reg++) {
        const int o = o0 + wv * 16 + quad * 4 + reg;
        #pragma unroll
        for (int nf = 0; nf < 4; nf++) {
            const size_t off = (((size_t)b * CIN + o) << 10) + l0 + nf * 16 + n;
            out[off] = acc[nf][reg] + bias_r[reg] + resid[off];
        }
    }
}

// ---------------------------------------------------------------------------
// Flash attention (round-7 validated core) + XCD-aware 1D grid swizzle:
// id = blockIdx.x; bh = id & 63 selects (b,h); i0 = (id>>6)*64.
// All 16 blocks sharing one (b,h)'s K/V have id ≡ bh (mod 64) -> same XCD
// under round-robin block->XCD dispatch -> K/V stays in that XCD's L2.
//  - K fragments direct from global, software-pipelined one tile ahead.
//  - V double-buffered in LDS -> one barrier per tile.
//  - ones-column denominator in registers; Ss stride 88 (2-way max).
// ---------------------------------------------------------------------------
__global__ __launch_bounds__(256) void attn_mfma(
    const short* __restrict__ qkvT, short* __restrict__ attnoT)
{
    __shared__ short Vt[2][32][80];                // swizzled: col ^= ((dv>>2)&7)<<3
    __shared__ __align__(16) char umem[64 * 88 * 2];
    short (*Ss)[88] = (short(*)[88])umem;          // [i][j] bf16 P (wave-private rows)
    float (*OtT)[38] = (float(*)[38])umem;         // [i][dv] fp32 epilogue

    const int t = threadIdx.x, lane = t & 63, wv = t >> 6;
    const int n = lane & 15, quad = lane >> 4;
    const int id = blockIdx.x;
    const int bh = id & 63;                        // same-(b,h) -> same XCD
    const int b = bh >> 3, h = bh & 7;
    const int i0 = (id >> 6) * 64;

    const short* base = qkvT + ((size_t)b << 10) * 768;
    const short* kbase = base + 256 + h * DH_;
    const short* vbase = base + 512 + h * DH_;

    // Q A-frag direct from global
    const short8 qa = *(const short8*)&base[(size_t)(i0 + wv * 16 + n) * 768 + h * DH_ + quad * 8];

    // constant ones-column B-frag: B[k][n]=1 iff n==0 (denominator column)
    short8 vf2;
    {
        const short one = (n == 0) ? (short)0x3F80 : (short)0;
        #pragma unroll
        for (int u = 0; u < 8; u++) vf2[u] = one;
    }

    f32x4 o_acc[3];
    #pragma unroll
    for (int nf = 0; nf < 3; nf++) o_acc[nf] = (f32x4){0.f, 0.f, 0.f, 0.f};

    const float K1 = 0.25503510f;    // (1/sqrt(32)) * log2(e)
    const float K2 = 11.54156036f;   // 8 * log2(e)

    const int jS = t >> 3, dsS = (t & 7) * 4;      // V stage roles

    // ---- prologue: stage V tile0 into buf0, load K frags tile0 ----
    #pragma unroll
    for (int rr = 0; rr < 2; rr++) {
        const int j = jS + rr * 32;
        const short4v v4 = *(const short4v*)&vbase[(size_t)j * 768 + dsS];
        #pragma unroll
        for (int u = 0; u < 4; u++) {
            const int dv = dsS + u;
            Vt[0][dv][j ^ (((dv >> 2) & 7) << 3)] = v4[u];
        }
    }
    short8 kf[4];
    #pragma unroll
    for (int f = 0; f < 4; f++)
        kf[f] = *(const short8*)&kbase[(size_t)(f * 16 + n) * 768 + quad * 8];

    for (int it = 0; it < 16; it++) {
        const int cur = it & 1;
        __syncthreads();   // prev iter's reads of buf cur done; buf cur writes visible

        short8 kf_n[4];
        if (it < 15) {     // stage tile it+1: V into buf cur^1, K into regs
            const int j0n = (it + 1) * 64;
            #pragma unroll
            for (int rr = 0; rr < 2; rr++) {
                const int j = jS + rr * 32;
                const short4v v4 = *(const short4v*)&vbase[(size_t)(j0n + j) * 768 + dsS];
                #pragma unroll
                for (int u = 0; u < 4; u++) {
                    const int dv = dsS + u;
                    Vt[cur ^ 1][dv][j ^ (((dv >> 2) & 7) << 3)] = v4[u];
                }
            }
            #pragma unroll
            for (int f = 0; f < 4; f++)
                kf_n[f] = *(const short8*)&kbase[(size_t)(j0n + f * 16 + n) * 768 + quad * 8];
        }

        // ---- S^T = K Q^T : lane holds S[i=wv*16+n][j=f*16+quad*4+r] ----
        #pragma unroll
        for (int f = 0; f < 4; f++) {
            f32x4 z = {0.f, 0.f, 0.f, 0.f};
            const f32x4 s = __builtin_amdgcn_mfma_f32_16x16x32_bf16(kf[f], qa, z, 0, 0, 0);
            const float p0 = exp2f(fmaf(s[0], K1, -K2));
            const float p1 = exp2f(fmaf(s[1], K1, -K2));
            const float p2 = exp2f(fmaf(s[2], K1, -K2));
            const float p3 = exp2f(fmaf(s[3], K1, -K2));
            uint2v pk = { pkbf2(p0, p1), pkbf2(p2, p3) };
            *(uint2v*)&Ss[wv * 16 + n][f * 16 + quad * 4] = pk;
        }
        // wave-private Ss rows: in-wave DS ordering, no barrier

        // ---- O += P V (vf2 = register ones-column -> denominator) ----
        #pragma unroll
        for (int kk = 0; kk < 2; kk++) {
            const short8 pf = *(const short8*)&Ss[wv * 16 + n][kk * 32 + quad * 8];
            #pragma unroll
            for (int nf = 0; nf < 2; nf++) {
                const int dv = nf * 16 + n;
                const int msk = ((dv >> 2) & 7) << 3;
                const short8 vf = *(const short8*)&Vt[cur][dv][(kk * 32 + quad * 8) ^ msk];
                o_acc[nf] = __builtin_amdgcn_mfma_f32_16x16x32_bf16(pf, vf, o_acc[nf], 0, 0, 0);
            }
            o_acc[2] = __builtin_amdgcn_mfma_f32_16x16x32_bf16(pf, vf2, o_acc[2], 0, 0, 0);
        }

        #pragma unroll
        for (int f = 0; f < 4; f++) kf[f] = kf_n[f];
    }

    __syncthreads();   // all PV reads of Ss done before OtT overwrites umem
    #pragma unroll
    for (int r = 0; r < 4; r++) {
        const float lv  = __shfl(o_acc[2][r], lane & 48, 64);
        const float inv = 1.f / lv;
        const int il = wv * 16 + quad * 4 + r;
        OtT[il][n]      = o_acc[0][r] * inv;
        OtT[il][16 + n] = o_acc[1][r] * inv;
    }
    __syncthreads();
    short* ob = attnoT + (((size_t)b << 10) + i0) * CIN + h * DH_;
    #pragma unroll
    for (int r = 0; r < 2; r++) {
        const int idx = t + r * 256;
        const int l = idx >> 3, cs = (idx & 7) * 4;
        uint2v pv;
        pv.x = pkbf2(OtT[l][cs],     OtT[l][cs + 1]);
        pv.y = pkbf2(OtT[l][cs + 2], OtT[l][cs + 3]);
        *(uint2v*)&ob[(size_t)l * CIN + cs] = pv;
    }
}

// ---------------------------------------------------------------------------
extern "C" void kernel_launch(void* const* d_in, const int* in_sizes, int n_in,
                              void* d_out, int out_size, void* d_ws, size_t ws_size,
                              hipStream_t stream) {
    const float* x      = (const float*)d_in[0];
    const float* w_qkv  = (const float*)d_in[1];
    const float* b_qkv  = (const float*)d_in[2];
    const float* w_proj = (const float*)d_in[3];
    const float* b_proj = (const float*)d_in[4];
    float* out = (float*)d_out;

    short* qkvT   = (short*)d_ws;                          // 12 MB [b][l][768]
    short* attnoT = qkvT + (size_t)B_ * L_ * 768;          // 4 MB  [b][l][256]

    qkv_gemm<<<dim3(16, 6, B_), 256, 0, stream>>>(x, w_qkv, b_qkv, qkvT);
    attn_mfma<<<dim3(1024), 256, 0, stream>>>(qkvT, attnoT);
    proj_gemm<<<dim3(16, 4, B_), 256, 0, stream>>>(attnoT, w_proj, b_proj, x, out);
}